// Round 1
// baseline (1567.138 us; speedup 1.0000x reference)
//
#include <hip/hip_runtime.h>

#define N_TOK 131072
#define KCODES 1024
#define DIM 64

// d_out layout (floats): [0]=loss, [1 .. 8388609)=quantized, [8388609]=perplexity,
// [8388610 ..)=encodings (131072 x 1024)
#define QUANT_OFF 1
#define PERP_OFF 8388609
#define ENC_OFF ((size_t)8388610)

__device__ __forceinline__ float wave_reduce_sum(float v) {
    #pragma unroll
    for (int o = 32; o > 0; o >>= 1) v += __shfl_xor(v, o, 64);
    return v;
}

// K0: c[j] = 0.5 * sum(e_j^2); zero counts + loss accumulator
__global__ void k0_prep(const float* __restrict__ ew, float* __restrict__ cbuf,
                        unsigned* __restrict__ counts, float* __restrict__ loss_acc) {
    int tid = threadIdx.x;
    int lane = tid & 63;
    int wg = blockIdx.x * 4 + (tid >> 6);   // 128 waves total
    int gt = blockIdx.x * 256 + tid;
    if (gt < KCODES) counts[gt] = 0u;
    if (gt == 0) *loss_acc = 0.0f;
    #pragma unroll
    for (int k = 0; k < 8; ++k) {
        int row = wg * 8 + k;
        float v = ew[row * 64 + lane];
        float s = wave_reduce_sum(v * v);
        if (lane == 0) cbuf[row] = 0.5f * s;
    }
}

// K1: per-token argmin + encodings zero-fill + one-hot + idx + histogram
__global__ __launch_bounds__(256) void k1_argmin(
        const float* __restrict__ x, const float* __restrict__ ew,
        const float* __restrict__ cbuf, float* __restrict__ out,
        int* __restrict__ idxbuf, unsigned* __restrict__ counts) {
    __shared__ float se[128 * 64];
    __shared__ float scc[128];
    int tid = threadIdx.x;
    size_t i = (size_t)blockIdx.x * 256 + tid;

    float4 x4[16];
    const float4* xp = (const float4*)(x + i * 64);
    #pragma unroll
    for (int q = 0; q < 16; ++q) x4[q] = xp[q];

    float2* enc2 = (float2*)(out + ENC_OFF) + (size_t)blockIdx.x * 131072;

    float best = -3.4e38f;
    int bestj = 0;

    for (int ch = 0; ch < 8; ++ch) {
        const float4* ep = (const float4*)(ew + ch * 128 * 64);
        float4* sp = (float4*)se;
        #pragma unroll
        for (int r = 0; r < 8; ++r) sp[tid + 256 * r] = ep[tid + 256 * r];
        if (tid < 128) scc[tid] = cbuf[ch * 128 + tid];
        __syncthreads();

        // interleave encodings zero-fill (overlaps with VALU-bound compute below)
        float2 z; z.x = 0.0f; z.y = 0.0f;
        #pragma unroll 4
        for (int u = 0; u < 64; ++u) enc2[ch * 16384 + u * 256 + tid] = z;

        for (int jj = 0; jj < 128; jj += 4) {
            const float4* e0 = (const float4*)(se + (jj + 0) * 64);
            const float4* e1 = (const float4*)(se + (jj + 1) * 64);
            const float4* e2 = (const float4*)(se + (jj + 2) * 64);
            const float4* e3 = (const float4*)(se + (jj + 3) * 64);
            float d0 = 0.f, d1 = 0.f, d2 = 0.f, d3 = 0.f;
            #pragma unroll
            for (int q = 0; q < 16; ++q) {
                float4 xv = x4[q];
                float4 a = e0[q];
                d0 = fmaf(xv.x, a.x, d0); d0 = fmaf(xv.y, a.y, d0);
                d0 = fmaf(xv.z, a.z, d0); d0 = fmaf(xv.w, a.w, d0);
                float4 b = e1[q];
                d1 = fmaf(xv.x, b.x, d1); d1 = fmaf(xv.y, b.y, d1);
                d1 = fmaf(xv.z, b.z, d1); d1 = fmaf(xv.w, b.w, d1);
                float4 c = e2[q];
                d2 = fmaf(xv.x, c.x, d2); d2 = fmaf(xv.y, c.y, d2);
                d2 = fmaf(xv.z, c.z, d2); d2 = fmaf(xv.w, c.w, d2);
                float4 d = e3[q];
                d3 = fmaf(xv.x, d.x, d3); d3 = fmaf(xv.y, d.y, d3);
                d3 = fmaf(xv.z, d.z, d3); d3 = fmaf(xv.w, d.w, d3);
            }
            float s0 = d0 - scc[jj + 0];
            float s1 = d1 - scc[jj + 1];
            float s2 = d2 - scc[jj + 2];
            float s3 = d3 - scc[jj + 3];
            int jb = ch * 128 + jj;
            if (s0 > best) { best = s0; bestj = jb + 0; }
            if (s1 > best) { best = s1; bestj = jb + 1; }
            if (s2 > best) { best = s2; bestj = jb + 2; }
            if (s3 > best) { best = s3; bestj = jb + 3; }
        }
        __syncthreads();
    }

    idxbuf[i] = bestj;
    atomicAdd(&counts[bestj], 1u);
    __syncthreads();   // drains vmcnt -> all zero stores of this block complete
    out[ENC_OFF + i * 1024 + (size_t)bestj] = 1.0f;
}

// K2: cluster-size smoothing, n, prefix sums (offsets+cursor), perplexity
__global__ void k2_stats(const float* __restrict__ ema_cs, const unsigned* __restrict__ counts,
                         float* __restrict__ smoothed, unsigned* __restrict__ cursor,
                         unsigned* __restrict__ offsets, float* __restrict__ out) {
    __shared__ unsigned sc[1024];
    __shared__ float sf[1024];
    int t = threadIdx.x;
    unsigned cnt = counts[t];
    float cs = 0.99f * ema_cs[t] + 0.01f * (float)cnt;

    sf[t] = cs; __syncthreads();
    for (int o = 512; o > 0; o >>= 1) { if (t < o) sf[t] += sf[t + o]; __syncthreads(); }
    float n = sf[0];
    __syncthreads();

    float sm = (cs + 1e-5f) / (n + 1024.0f * 1e-5f) * n;
    smoothed[t] = sm;

    sc[t] = cnt; __syncthreads();
    for (int o = 1; o < 1024; o <<= 1) {
        unsigned v = (t >= o) ? sc[t - o] : 0u;
        __syncthreads();
        sc[t] += v;
        __syncthreads();
    }
    unsigned excl = sc[t] - cnt;
    offsets[t] = excl;
    cursor[t] = excl;

    float p = (float)cnt / 131072.0f;
    float term = p * logf(p + 1e-10f);
    sf[t] = term; __syncthreads();
    for (int o = 512; o > 0; o >>= 1) { if (t < o) sf[t] += sf[t + o]; __syncthreads(); }
    if (t == 0) out[PERP_OFF] = expf(-sf[0]);
}

// K3: counting-sort scatter
__global__ void k3_scatter(const int* __restrict__ idxbuf, unsigned* __restrict__ cursor,
                           int* __restrict__ toklist) {
    int i = blockIdx.x * 256 + threadIdx.x;
    int ii = idxbuf[i];
    unsigned pos = atomicAdd(&cursor[ii], 1u);
    toklist[pos] = i;
}

// K4: per-cluster dw sum + EMA + embedding_new
__global__ void k4_update(const float* __restrict__ x, const float* __restrict__ ema_w,
                          const int* __restrict__ toklist, const unsigned* __restrict__ offsets,
                          const unsigned* __restrict__ counts, const float* __restrict__ smoothed,
                          float* __restrict__ embnew) {
    __shared__ float part[4][64];
    int k = blockIdx.x;
    int lane = threadIdx.x & 63, w = threadIdx.x >> 6;
    unsigned off = offsets[k], cnt = counts[k];
    float acc = 0.0f;
    for (unsigned t = off + w; t < off + cnt; t += 4) {
        int tok = toklist[t];
        acc += x[(size_t)tok * 64 + lane];
    }
    part[w][lane] = acc;
    __syncthreads();
    if (w == 0) {
        float dw = part[0][lane] + part[1][lane] + part[2][lane] + part[3][lane];
        float en = ema_w[k * 64 + lane] * 0.99f + 0.01f * dw;
        embnew[k * 64 + lane] = en / smoothed[k];
    }
}

// K5: quantized output + loss accumulation (wave handles 64 tokens)
__global__ void k5_output(const float* __restrict__ x, const float* __restrict__ embnew,
                          const int* __restrict__ idxbuf, float* __restrict__ out,
                          float* __restrict__ loss_acc) {
    int tid = threadIdx.x;
    int lane = tid & 63, w = tid >> 6;
    size_t wbase = ((size_t)blockIdx.x * 4 + w) * 64;
    int myidx = idxbuf[wbase + lane];
    float ls = 0.0f;
    #pragma unroll 4
    for (int t = 0; t < 64; ++t) {
        size_t i = wbase + t;
        int ii = __shfl(myidx, t, 64);
        float q = embnew[(size_t)ii * 64 + lane];
        float xv = x[i * 64 + lane];
        out[QUANT_OFF + i * 64 + lane] = xv + (q - xv);  // straight-through, mimic ref fp ops
        float diff = q - xv;
        ls = fmaf(diff, diff, ls);
    }
    ls = wave_reduce_sum(ls);
    if (lane == 0) atomicAdd(loss_acc, ls);
}

// K6: final loss scalar
__global__ void k6_loss(const float* __restrict__ loss_acc, float* __restrict__ out) {
    if (threadIdx.x == 0) out[0] = 0.25f * 0.5f * (*loss_acc) / 131072.0f;
}

extern "C" void kernel_launch(void* const* d_in, const int* in_sizes, int n_in,
                              void* d_out, int out_size, void* d_ws, size_t ws_size,
                              hipStream_t stream) {
    const float* x      = (const float*)d_in[0];
    const float* ew     = (const float*)d_in[1];
    const float* emaw   = (const float*)d_in[2];
    const float* emacs  = (const float*)d_in[3];
    float* out = (float*)d_out;
    float* wsf = (float*)d_ws;

    float*    cbuf     = wsf;                       // 1024
    float*    smoothed = wsf + 1024;                // 1024
    unsigned* counts   = (unsigned*)(wsf + 2048);   // 1024
    unsigned* cursor   = (unsigned*)(wsf + 3072);   // 1024
    unsigned* offsets  = (unsigned*)(wsf + 4096);   // 1024
    float*    loss_acc = wsf + 5120;                // 1
    int*      idxbuf   = (int*)(wsf + 5184);        // 131072
    int*      toklist  = idxbuf + N_TOK;            // 131072
    float*    embnew   = wsf + 5184 + 2 * N_TOK;    // 65536

    hipLaunchKernelGGL(k0_prep,   dim3(32),   dim3(256),  0, stream, ew, cbuf, counts, loss_acc);
    hipLaunchKernelGGL(k1_argmin, dim3(512),  dim3(256),  0, stream, x, ew, cbuf, out, idxbuf, counts);
    hipLaunchKernelGGL(k2_stats,  dim3(1),    dim3(1024), 0, stream, emacs, counts, smoothed, cursor, offsets, out);
    hipLaunchKernelGGL(k3_scatter,dim3(512),  dim3(256),  0, stream, idxbuf, cursor, toklist);
    hipLaunchKernelGGL(k4_update, dim3(1024), dim3(256),  0, stream, x, emaw, toklist, offsets, counts, smoothed, embnew);
    hipLaunchKernelGGL(k5_output, dim3(512),  dim3(256),  0, stream, x, embnew, idxbuf, out, loss_acc);
    hipLaunchKernelGGL(k6_loss,   dim3(1),    dim3(64),   0, stream, loss_acc, out);
}

// Round 2
// 1014.427 us; speedup vs baseline: 1.5448x; 1.5448x over previous
//
#include <hip/hip_runtime.h>

#define N_TOK 131072
#define KCODES 1024
#define DIM 64

// d_out layout (floats): [0]=loss, [1..)=quantized, [8388609]=perplexity, [8388610..)=encodings
#define QUANT_OFF 1
#define PERP_OFF 8388609
#define ENC_OFF ((size_t)8388610)

__device__ __forceinline__ float wave_reduce_sum(float v) {
    #pragma unroll
    for (int o = 32; o > 0; o >>= 1) v += __shfl_xor(v, o, 64);
    return v;
}

// K0: cbuf[j] = 0.5*sum(e_j^2); zero counts, loss, dwacc
__global__ void k0_prep(const float* __restrict__ ew, float* __restrict__ cbuf,
                        unsigned* __restrict__ counts, float* __restrict__ loss_acc,
                        float* __restrict__ dwacc) {
    int tid = threadIdx.x;
    int lane = tid & 63;
    int wg = blockIdx.x * 4 + (tid >> 6);   // 128 waves
    int gt = blockIdx.x * 256 + tid;        // 8192 threads
    if (gt < KCODES) counts[gt] = 0u;
    if (gt == 0) *loss_acc = 0.0f;
    #pragma unroll
    for (int z = 0; z < 8; ++z) dwacc[gt * 8 + z] = 0.0f;   // 65536 floats
    #pragma unroll
    for (int k = 0; k < 8; ++k) {
        int row = wg * 8 + k;
        float v = ew[row * 64 + lane];
        float s = wave_reduce_sum(v * v);
        if (lane == 0) cbuf[row] = 0.5f * s;
    }
}

// K1: K-split argmin. Block = (token-group of 256) x (code-chunk of 256).
// Grid 2048 -> 8 blocks/CU avg, 4 resident (32KB LDS) = 16 waves/CU.
__global__ __launch_bounds__(256, 4) void k1_argmin(
        const float* __restrict__ x, const float* __restrict__ ew,
        const float* __restrict__ cbuf, float* __restrict__ out,
        float* __restrict__ candv, int* __restrict__ candi) {
    __shared__ float se[128 * 64];
    __shared__ float scc[128];
    int tid = threadIdx.x;
    int tg = blockIdx.x >> 2;
    int cc = blockIdx.x & 3;
    size_t tok0 = (size_t)tg * 256;
    int code0 = cc * 256;

    float4 x4[16];
    const float4* xp = (const float4*)(x + (tok0 + tid) * 64);
    #pragma unroll
    for (int q = 0; q < 16; ++q) x4[q] = xp[q];

    float best = -3.4e38f;
    int bestj = 0;

    for (int ch = 0; ch < 2; ++ch) {
        int cbase = code0 + ch * 128;
        const float4* ep = (const float4*)(ew + (size_t)cbase * 64);
        float4* sp = (float4*)se;
        #pragma unroll
        for (int r = 0; r < 8; ++r) sp[tid + 256 * r] = ep[tid + 256 * r];
        if (tid < 128) scc[tid] = cbuf[cbase + tid];
        __syncthreads();

        // zero-fill my block's encodings sub-rectangle (256 tokens x 256 codes),
        // interleaved so the 512MB write overlaps the VALU-bound compute.
        // float2: ENC_OFF is only 8B-aligned. 2 rows per step, 32 steps per chunk.
        float2 z; z.x = 0.0f; z.y = 0.0f;
        #pragma unroll 4
        for (int s = 0; s < 32; ++s) {
            int step = ch * 32 + s;
            size_t row = tok0 + step * 2 + (tid >> 7);
            ((float2*)(out + ENC_OFF + row * 1024 + code0))[tid & 127] = z;
        }

        for (int jj = 0; jj < 128; jj += 4) {
            const float4* e0 = (const float4*)(se + (jj + 0) * 64);
            const float4* e1 = (const float4*)(se + (jj + 1) * 64);
            const float4* e2 = (const float4*)(se + (jj + 2) * 64);
            const float4* e3 = (const float4*)(se + (jj + 3) * 64);
            float d0 = 0.f, d1 = 0.f, d2 = 0.f, d3 = 0.f;
            #pragma unroll
            for (int q = 0; q < 16; ++q) {
                float4 xv = x4[q];
                float4 a = e0[q];
                d0 = fmaf(xv.x, a.x, d0); d0 = fmaf(xv.y, a.y, d0);
                d0 = fmaf(xv.z, a.z, d0); d0 = fmaf(xv.w, a.w, d0);
                float4 b = e1[q];
                d1 = fmaf(xv.x, b.x, d1); d1 = fmaf(xv.y, b.y, d1);
                d1 = fmaf(xv.z, b.z, d1); d1 = fmaf(xv.w, b.w, d1);
                float4 c = e2[q];
                d2 = fmaf(xv.x, c.x, d2); d2 = fmaf(xv.y, c.y, d2);
                d2 = fmaf(xv.z, c.z, d2); d2 = fmaf(xv.w, c.w, d2);
                float4 d = e3[q];
                d3 = fmaf(xv.x, d.x, d3); d3 = fmaf(xv.y, d.y, d3);
                d3 = fmaf(xv.z, d.z, d3); d3 = fmaf(xv.w, d.w, d3);
            }
            float s0 = d0 - scc[jj + 0];
            float s1 = d1 - scc[jj + 1];
            float s2 = d2 - scc[jj + 2];
            float s3 = d3 - scc[jj + 3];
            int jb = cbase + jj;
            if (s0 > best) { best = s0; bestj = jb + 0; }
            if (s1 > best) { best = s1; bestj = jb + 1; }
            if (s2 > best) { best = s2; bestj = jb + 2; }
            if (s3 > best) { best = s3; bestj = jb + 3; }
        }
        __syncthreads();
    }
    size_t i = tok0 + tid;
    candv[(size_t)cc * N_TOK + i] = best;
    candi[(size_t)cc * N_TOK + i] = bestj;
}

// K1b: merge 4 candidates per token, write idx + one-hot + histogram
__global__ void k1b_merge(const float* __restrict__ candv, const int* __restrict__ candi,
                          float* __restrict__ out, int* __restrict__ idxbuf,
                          unsigned* __restrict__ counts) {
    int i = blockIdx.x * 256 + threadIdx.x;
    float best = candv[i];
    int bestj = candi[i];
    #pragma unroll
    for (int c = 1; c < 4; ++c) {
        float v = candv[(size_t)c * N_TOK + i];
        int j = candi[(size_t)c * N_TOK + i];
        if (v > best) { best = v; bestj = j; }   // chunk-ascending: ties keep lower idx
    }
    idxbuf[i] = bestj;
    atomicAdd(&counts[bestj], 1u);
    out[ENC_OFF + (size_t)i * 1024 + (size_t)bestj] = 1.0f;
}

// K2: cluster-size smoothing, n, prefix sums, perplexity (single block, small)
__global__ void k2_stats(const float* __restrict__ ema_cs, const unsigned* __restrict__ counts,
                         float* __restrict__ smoothed, unsigned* __restrict__ cursor,
                         unsigned* __restrict__ offsets, float* __restrict__ out) {
    __shared__ unsigned sc[1024];
    __shared__ float sf[1024];
    int t = threadIdx.x;
    unsigned cnt = counts[t];
    float cs = 0.99f * ema_cs[t] + 0.01f * (float)cnt;

    sf[t] = cs; __syncthreads();
    for (int o = 512; o > 0; o >>= 1) { if (t < o) sf[t] += sf[t + o]; __syncthreads(); }
    float n = sf[0];
    __syncthreads();

    float sm = (cs + 1e-5f) / (n + 1024.0f * 1e-5f) * n;
    smoothed[t] = sm;

    sc[t] = cnt; __syncthreads();
    for (int o = 1; o < 1024; o <<= 1) {
        unsigned v = (t >= o) ? sc[t - o] : 0u;
        __syncthreads();
        sc[t] += v;
        __syncthreads();
    }
    unsigned excl = sc[t] - cnt;
    offsets[t] = excl;
    cursor[t] = excl;

    float p = (float)cnt / 131072.0f;
    float term = p * logf(p + 1e-10f);
    sf[t] = term; __syncthreads();
    for (int o = 512; o > 0; o >>= 1) { if (t < o) sf[t] += sf[t + o]; __syncthreads(); }
    if (t == 0) out[PERP_OFF] = expf(-sf[0]);
}

// K3: counting-sort scatter (also records sorted cluster id per position)
__global__ void k3_scatter(const int* __restrict__ idxbuf, unsigned* __restrict__ cursor,
                           int* __restrict__ toklist, int* __restrict__ clustid) {
    int i = blockIdx.x * 256 + threadIdx.x;
    int ii = idxbuf[i];
    unsigned pos = atomicAdd(&cursor[ii], 1u);
    toklist[pos] = i;
    clustid[pos] = ii;
}

// K4a: balanced dw accumulation over sorted positions.
// Each wave: 32 consecutive positions; register accumulate, flush at cluster boundary.
__global__ void k4a_dw(const float* __restrict__ x, const int* __restrict__ toklist,
                       const int* __restrict__ clustid, float* __restrict__ dwacc) {
    int lane = threadIdx.x & 63, w = threadIdx.x >> 6;
    int p0 = blockIdx.x * 128 + w * 32;
    int cur = clustid[p0];
    float acc = 0.0f;
    #pragma unroll 4
    for (int t = 0; t < 32; ++t) {
        int pos = p0 + t;
        int c = clustid[pos];      // wave-uniform
        int tok = toklist[pos];    // wave-uniform
        float v = x[(size_t)tok * 64 + lane];
        if (c != cur) {
            atomicAdd(&dwacc[(size_t)cur * 64 + lane], acc);
            acc = 0.0f; cur = c;
        }
        acc += v;
    }
    atomicAdd(&dwacc[(size_t)cur * 64 + lane], acc);
}

// K4b: embedding_new = (ema_w*decay + (1-decay)*dw) / smoothed
__global__ void k4b_emb(const float* __restrict__ emaw, const float* __restrict__ dwacc,
                        const float* __restrict__ smoothed, float* __restrict__ embnew) {
    int t = blockIdx.x * 256 + threadIdx.x;   // 65536
    int k = t >> 6;
    embnew[t] = (emaw[t] * 0.99f + 0.01f * dwacc[t]) / smoothed[k];
}

// K5: quantized output + loss (wave handles 32 tokens)
__global__ void k5_output(const float* __restrict__ x, const float* __restrict__ embnew,
                          const int* __restrict__ idxbuf, float* __restrict__ out,
                          float* __restrict__ loss_acc) {
    int tid = threadIdx.x;
    int lane = tid & 63, w = tid >> 6;
    size_t wbase = ((size_t)blockIdx.x * 4 + w) * 32;
    int myidx = idxbuf[wbase + (lane & 31)];
    float ls = 0.0f;
    #pragma unroll 4
    for (int t = 0; t < 32; ++t) {
        size_t i = wbase + t;
        int ii = __shfl(myidx, t, 64);
        float q = embnew[(size_t)ii * 64 + lane];
        float xv = x[i * 64 + lane];
        out[QUANT_OFF + i * 64 + lane] = xv + (q - xv);
        float diff = q - xv;
        ls = fmaf(diff, diff, ls);
    }
    ls = wave_reduce_sum(ls);
    if (lane == 0) atomicAdd(loss_acc, ls);
}

// K6: final loss scalar
__global__ void k6_loss(const float* __restrict__ loss_acc, float* __restrict__ out) {
    if (threadIdx.x == 0) out[0] = 0.25f * 0.5f * (*loss_acc) / 131072.0f;
}

extern "C" void kernel_launch(void* const* d_in, const int* in_sizes, int n_in,
                              void* d_out, int out_size, void* d_ws, size_t ws_size,
                              hipStream_t stream) {
    const float* x     = (const float*)d_in[0];
    const float* ew    = (const float*)d_in[1];
    const float* emaw  = (const float*)d_in[2];
    const float* emacs = (const float*)d_in[3];
    float* out = (float*)d_out;
    float* wsf = (float*)d_ws;

    float*    cbuf     = wsf;                          // 1024
    float*    smoothed = wsf + 1024;                   // 1024
    unsigned* counts   = (unsigned*)(wsf + 2048);      // 1024
    unsigned* cursor   = (unsigned*)(wsf + 3072);      // 1024
    unsigned* offsets  = (unsigned*)(wsf + 4096);      // 1024
    float*    loss_acc = wsf + 5120;                   // 1 (+pad)
    int*      idxbuf   = (int*)(wsf + 5184);           // 131072
    int*      toklist  = idxbuf + N_TOK;               // 131072
    int*      clustid  = toklist + N_TOK;              // 131072
    float*    embnew   = wsf + 5184 + 3 * N_TOK;       // 65536
    float*    dwacc    = embnew + 65536;               // 65536
    float*    candv    = dwacc + 65536;                // 4*131072
    int*      candi    = (int*)(candv + 4 * N_TOK);    // 4*131072

    hipLaunchKernelGGL(k0_prep,   dim3(32),   dim3(256),  0, stream, ew, cbuf, counts, loss_acc, dwacc);
    hipLaunchKernelGGL(k1_argmin, dim3(2048), dim3(256),  0, stream, x, ew, cbuf, out, candv, candi);
    hipLaunchKernelGGL(k1b_merge, dim3(512),  dim3(256),  0, stream, candv, candi, out, idxbuf, counts);
    hipLaunchKernelGGL(k2_stats,  dim3(1),    dim3(1024), 0, stream, emacs, counts, smoothed, cursor, offsets, out);
    hipLaunchKernelGGL(k3_scatter,dim3(512),  dim3(256),  0, stream, idxbuf, cursor, toklist, clustid);
    hipLaunchKernelGGL(k4a_dw,    dim3(1024), dim3(256),  0, stream, x, toklist, clustid, dwacc);
    hipLaunchKernelGGL(k4b_emb,   dim3(256),  dim3(256),  0, stream, emaw, dwacc, smoothed, embnew);
    hipLaunchKernelGGL(k5_output, dim3(1024), dim3(256),  0, stream, x, embnew, idxbuf, out, loss_acc);
    hipLaunchKernelGGL(k6_loss,   dim3(1),    dim3(64),   0, stream, loss_acc, out);
}

// Round 3
// 716.704 us; speedup vs baseline: 2.1866x; 1.4154x over previous
//
#include <hip/hip_runtime.h>

#define N_TOK 131072
#define KCODES 1024
#define DIM 64
#define QUANT_OFF 1
#define PERP_OFF 8388609
#define ENC_OFF ((size_t)8388610)

typedef __attribute__((ext_vector_type(8))) short short8v;   // 8 bf16 (4 VGPRs)
typedef __attribute__((ext_vector_type(4))) float f32x4;     // 4 fp32 acc

__device__ __forceinline__ float wave_reduce_sum(float v) {
    #pragma unroll
    for (int o = 32; o > 0; o >>= 1) v += __shfl_xor(v, o, 64);
    return v;
}

__device__ __forceinline__ unsigned bf16_rne(float f) {
    unsigned u = __float_as_uint(f);
    return (u + 0x7FFFu + ((u >> 16) & 1u)) >> 16;
}

// convert 8 fp32 -> (hi, lo) bf16x8 split: f == hi + lo to ~2^-17 rel
__device__ __forceinline__ void cvt8(const float4 a, const float4 b,
                                     short8v* h, short8v* l) {
    float f[8] = {a.x, a.y, a.z, a.w, b.x, b.y, b.z, b.w};
    #pragma unroll
    for (int j = 0; j < 8; ++j) {
        unsigned hb = bf16_rne(f[j]);
        float fh = __uint_as_float(hb << 16);
        unsigned lb = bf16_rne(f[j] - fh);
        (*h)[j] = (short)hb;
        (*l)[j] = (short)lb;
    }
}

// K0: cbuf[j] = 0.5*sum(e_j^2); zero dwacc + loss
__global__ void k0_prep(const float* __restrict__ ew, float* __restrict__ cbuf,
                        float* __restrict__ loss_acc, float* __restrict__ dwacc) {
    int tid = threadIdx.x;
    int lane = tid & 63;
    int wg = blockIdx.x * 4 + (tid >> 6);   // 128 waves
    int gt = blockIdx.x * 256 + tid;        // 8192 threads
    if (gt == 0) *loss_acc = 0.0f;
    #pragma unroll
    for (int z = 0; z < 8; ++z) dwacc[gt * 8 + z] = 0.0f;
    #pragma unroll
    for (int k = 0; k < 8; ++k) {
        int row = wg * 8 + k;
        float v = ew[row * 64 + lane];
        float s = wave_reduce_sum(v * v);
        if (lane == 0) cbuf[row] = 0.5f * s;
    }
}

// K1: MFMA argmin (bf16 4-term split) + encodings zero-fill + LDS hist/rank + blockhist
// block = 256 thr (4 waves x 64 tokens), grid 512. Codes looped in 8 chunks of 128.
__global__ __launch_bounds__(256) void k1_argmin(
        const float* __restrict__ x, const float* __restrict__ ew,
        const float* __restrict__ cbuf, float* __restrict__ out,
        unsigned* __restrict__ idxbuf, unsigned* __restrict__ blockhist) {
    __shared__ unsigned short EH[128 * 64];   // bf16 hi, XOR-swizzled rows
    __shared__ unsigned short EL[128 * 64];   // bf16 lo
    __shared__ float scc[128];
    __shared__ unsigned hist[1024];

    int tid = threadIdx.x;
    int lane = tid & 63;
    int wv = tid >> 6;
    int l15 = lane & 15;
    int l4 = lane >> 4;
    size_t t0 = (size_t)blockIdx.x * 256;
    size_t t0w = t0 + (size_t)wv * 64;

    #pragma unroll
    for (int q = 0; q < 4; ++q) hist[q * 256 + tid] = 0u;

    // A fragments: wave's 64 tokens (4 row-tiles), K=64 (2 slabs), hi+lo
    short8v ah[4][2], al[4][2];
    #pragma unroll
    for (int rt = 0; rt < 4; ++rt) {
        const float* xp = x + (t0w + rt * 16 + l15) * 64 + l4 * 8;
        #pragma unroll
        for (int s = 0; s < 2; ++s) {
            float4 a = *(const float4*)(xp + s * 32);
            float4 b = *(const float4*)(xp + s * 32 + 4);
            cvt8(a, b, &ah[rt][s], &al[rt][s]);
        }
    }

    float best[4][4];
    int bidx[4][4];
    #pragma unroll
    for (int rt = 0; rt < 4; ++rt)
        #pragma unroll
        for (int r = 0; r < 4; ++r) { best[rt][r] = -3.4e38f; bidx[rt][r] = 0; }

    for (int ch = 0; ch < 8; ++ch) {
        int c0 = ch * 128;
        // stage 128 codes: thread t -> row r=t>>1, col half h=t&1 (32 elems)
        {
            int r = tid >> 1, h = tid & 1;
            const float* ep = ew + (size_t)(c0 + r) * 64 + h * 32;
            #pragma unroll
            for (int q = 0; q < 4; ++q) {
                float4 a = *(const float4*)(ep + q * 8);
                float4 b = *(const float4*)(ep + q * 8 + 4);
                short8v hv, lv;
                cvt8(a, b, &hv, &lv);
                int byteoff = (r * 128 + h * 64 + q * 16) ^ ((r & 7) << 4);
                *(short8v*)((char*)EH + byteoff) = hv;
                *(short8v*)((char*)EL + byteoff) = lv;
            }
            if (tid < 128) scc[tid] = cbuf[c0 + tid];
        }
        __syncthreads();

        // zero-fill encodings rows [t0+ch*32, +32): 128KB, overlaps MFMA below
        {
            float2 z; z.x = 0.0f; z.y = 0.0f;
            float* base = out + ENC_OFF + (t0 + (size_t)ch * 32) * 1024;
            #pragma unroll 4
            for (int u = 0; u < 64; ++u) {
                int idx = u * 256 + tid;      // 0..16383
                int row = idx >> 9;
                int c2 = idx & 511;
                *(float2*)(base + (size_t)row * 1024 + c2 * 2) = z;
            }
        }

        #pragma unroll 2
        for (int ct = 0; ct < 8; ++ct) {
            int crow = ct * 16 + l15;
            int swz = (crow & 7) << 4;
            int b0 = (crow * 128 + l4 * 16) ^ swz;
            int b1 = (crow * 128 + 64 + l4 * 16) ^ swz;
            short8v bh0 = *(short8v*)((char*)EH + b0);
            short8v bl0 = *(short8v*)((char*)EL + b0);
            short8v bh1 = *(short8v*)((char*)EH + b1);
            short8v bl1 = *(short8v*)((char*)EL + b1);
            float sccv = scc[crow];
            int cid = c0 + crow;
            #pragma unroll
            for (int rt = 0; rt < 4; ++rt) {
                f32x4 acc = {0.f, 0.f, 0.f, 0.f};
                acc = __builtin_amdgcn_mfma_f32_16x16x32_bf16(ah[rt][0], bh0, acc, 0, 0, 0);
                acc = __builtin_amdgcn_mfma_f32_16x16x32_bf16(al[rt][0], bh0, acc, 0, 0, 0);
                acc = __builtin_amdgcn_mfma_f32_16x16x32_bf16(ah[rt][0], bl0, acc, 0, 0, 0);
                acc = __builtin_amdgcn_mfma_f32_16x16x32_bf16(al[rt][0], bl0, acc, 0, 0, 0);
                acc = __builtin_amdgcn_mfma_f32_16x16x32_bf16(ah[rt][1], bh1, acc, 0, 0, 0);
                acc = __builtin_amdgcn_mfma_f32_16x16x32_bf16(al[rt][1], bh1, acc, 0, 0, 0);
                acc = __builtin_amdgcn_mfma_f32_16x16x32_bf16(ah[rt][1], bl1, acc, 0, 0, 0);
                acc = __builtin_amdgcn_mfma_f32_16x16x32_bf16(al[rt][1], bl1, acc, 0, 0, 0);
                #pragma unroll
                for (int r = 0; r < 4; ++r) {
                    float sc = acc[r] - sccv;
                    if (sc > best[rt][r]) { best[rt][r] = sc; bidx[rt][r] = cid; }
                }
            }
        }
        __syncthreads();
    }

    // reduce (best,idx) across the 16 lanes of each col-group; ties -> lower idx
    #pragma unroll
    for (int rt = 0; rt < 4; ++rt)
        #pragma unroll
        for (int r = 0; r < 4; ++r) {
            float v = best[rt][r];
            int iv = bidx[rt][r];
            #pragma unroll
            for (int o = 1; o < 16; o <<= 1) {
                float vo = __shfl_xor(v, o, 64);
                int io = __shfl_xor(iv, o, 64);
                if (vo > v || (vo == v && io < iv)) { v = vo; iv = io; }
            }
            best[rt][r] = v;
            bidx[rt][r] = iv;
        }

    if (l15 == 0) {
        #pragma unroll
        for (int rt = 0; rt < 4; ++rt)
            #pragma unroll
            for (int r = 0; r < 4; ++r) {
                int bin = bidx[rt][r];
                unsigned rank = atomicAdd(&hist[bin], 1u);
                idxbuf[t0w + rt * 16 + l4 * 4 + r] = (unsigned)bin | (rank << 10);
            }
    }
    __syncthreads();
    #pragma unroll
    for (int q = 0; q < 4; ++q)
        blockhist[(size_t)blockIdx.x * 1024 + q * 256 + tid] = hist[q * 256 + tid];
}

// K2a: per-bin exclusive scan over 512 block-histograms (wave per bin) -> blockbase, counts
__global__ void k2a_scan(const unsigned* __restrict__ blockhist,
                         unsigned* __restrict__ blockbase,
                         unsigned* __restrict__ counts) {
    int lane = threadIdx.x & 63;
    int bin = blockIdx.x * 4 + (threadIdx.x >> 6);
    unsigned v[8];
    unsigned s = 0;
    #pragma unroll
    for (int j = 0; j < 8; ++j) v[j] = blockhist[(size_t)(lane * 8 + j) * 1024 + bin];
    #pragma unroll
    for (int j = 0; j < 8; ++j) { unsigned t = v[j]; v[j] = s; s += t; }
    unsigned inc = s;
    for (int o = 1; o < 64; o <<= 1) {
        unsigned n = __shfl_up(inc, o, 64);
        if (lane >= o) inc += n;
    }
    unsigned excl = inc - s;
    #pragma unroll
    for (int j = 0; j < 8; ++j)
        blockbase[(size_t)(lane * 8 + j) * 1024 + bin] = excl + v[j];
    if (lane == 63) counts[bin] = inc;
}

// K2: smoothing, bin offsets, perplexity
__global__ void k2_stats(const float* __restrict__ ema_cs, const unsigned* __restrict__ counts,
                         float* __restrict__ smoothed, unsigned* __restrict__ offsets,
                         float* __restrict__ out) {
    __shared__ unsigned sc[1024];
    __shared__ float sf[1024];
    int t = threadIdx.x;
    unsigned cnt = counts[t];
    float cs = 0.99f * ema_cs[t] + 0.01f * (float)cnt;

    sf[t] = cs; __syncthreads();
    for (int o = 512; o > 0; o >>= 1) { if (t < o) sf[t] += sf[t + o]; __syncthreads(); }
    float n = sf[0];
    __syncthreads();
    smoothed[t] = (cs + 1e-5f) / (n + 1024.0f * 1e-5f) * n;

    sc[t] = cnt; __syncthreads();
    for (int o = 1; o < 1024; o <<= 1) {
        unsigned v = (t >= o) ? sc[t - o] : 0u;
        __syncthreads();
        sc[t] += v;
        __syncthreads();
    }
    offsets[t] = sc[t] - cnt;

    float p = (float)cnt / 131072.0f;
    sf[t] = p * logf(p + 1e-10f); __syncthreads();
    for (int o = 512; o > 0; o >>= 1) { if (t < o) sf[t] += sf[t + o]; __syncthreads(); }
    if (t == 0) out[PERP_OFF] = expf(-sf[0]);
}

// K3: atomic-free scatter (computed position) + one-hot write
__global__ void k3_scatter(const unsigned* __restrict__ idxbuf,
                           const unsigned* __restrict__ offsets,
                           const unsigned* __restrict__ blockbase,
                           int* __restrict__ toklist, int* __restrict__ clustid,
                           float* __restrict__ out) {
    int i = blockIdx.x * 256 + threadIdx.x;
    unsigned v = idxbuf[i];
    unsigned bin = v & 1023u;
    unsigned rank = v >> 10;
    unsigned pos = offsets[bin] + blockbase[(size_t)(i >> 8) * 1024 + bin] + rank;
    toklist[pos] = i;
    clustid[pos] = (int)bin;
    out[ENC_OFF + (size_t)i * 1024 + bin] = 1.0f;
}

// K4a: balanced dw accumulation over sorted positions
__global__ void k4a_dw(const float* __restrict__ x, const int* __restrict__ toklist,
                       const int* __restrict__ clustid, float* __restrict__ dwacc) {
    int lane = threadIdx.x & 63, w = threadIdx.x >> 6;
    int p0 = blockIdx.x * 128 + w * 32;
    int cur = clustid[p0];
    float acc = 0.0f;
    #pragma unroll 4
    for (int t = 0; t < 32; ++t) {
        int pos = p0 + t;
        int c = clustid[pos];
        int tok = toklist[pos];
        float v = x[(size_t)tok * 64 + lane];
        if (c != cur) {
            atomicAdd(&dwacc[(size_t)cur * 64 + lane], acc);
            acc = 0.0f; cur = c;
        }
        acc += v;
    }
    atomicAdd(&dwacc[(size_t)cur * 64 + lane], acc);
}

// K4b: embedding_new = (ema_w*decay + (1-decay)*dw) / smoothed
__global__ void k4b_emb(const float* __restrict__ emaw, const float* __restrict__ dwacc,
                        const float* __restrict__ smoothed, float* __restrict__ embnew) {
    int t = blockIdx.x * 256 + threadIdx.x;
    int k = t >> 6;
    embnew[t] = (emaw[t] * 0.99f + 0.01f * dwacc[t]) / smoothed[k];
}

// K5: quantized output + loss (wave handles 32 tokens)
__global__ void k5_output(const float* __restrict__ x, const float* __restrict__ embnew,
                          const unsigned* __restrict__ idxbuf, float* __restrict__ out,
                          float* __restrict__ loss_acc) {
    int tid = threadIdx.x;
    int lane = tid & 63, w = tid >> 6;
    size_t wbase = ((size_t)blockIdx.x * 4 + w) * 32;
    int myidx = (int)(idxbuf[wbase + (lane & 31)] & 1023u);
    float ls = 0.0f;
    #pragma unroll 4
    for (int t = 0; t < 32; ++t) {
        size_t i = wbase + t;
        int ii = __shfl(myidx, t, 64);
        float q = embnew[(size_t)ii * 64 + lane];
        float xv = x[i * 64 + lane];
        out[QUANT_OFF + i * 64 + lane] = xv + (q - xv);
        float diff = q - xv;
        ls = fmaf(diff, diff, ls);
    }
    ls = wave_reduce_sum(ls);
    if (lane == 0) atomicAdd(loss_acc, ls);
}

// K6: final loss scalar
__global__ void k6_loss(const float* __restrict__ loss_acc, float* __restrict__ out) {
    if (threadIdx.x == 0) out[0] = 0.25f * 0.5f * (*loss_acc) / 131072.0f;
}

extern "C" void kernel_launch(void* const* d_in, const int* in_sizes, int n_in,
                              void* d_out, int out_size, void* d_ws, size_t ws_size,
                              hipStream_t stream) {
    const float* x     = (const float*)d_in[0];
    const float* ew    = (const float*)d_in[1];
    const float* emaw  = (const float*)d_in[2];
    const float* emacs = (const float*)d_in[3];
    float* out = (float*)d_out;
    float* wsf = (float*)d_ws;

    float*    cbuf      = wsf;                                // 1024
    float*    smoothed  = wsf + 1024;                         // 1024
    unsigned* offsets   = (unsigned*)(wsf + 2048);            // 1024
    unsigned* counts    = (unsigned*)(wsf + 3072);            // 1024
    float*    loss_acc  = wsf + 4096;                         // 64 (pad)
    unsigned* idxbuf    = (unsigned*)(wsf + 4160);            // 131072
    int*      toklist   = (int*)(wsf + 4160 + N_TOK);         // 131072
    int*      clustid   = toklist + N_TOK;                    // 131072
    float*    dwacc     = wsf + 4160 + 3 * N_TOK;             // 65536
    float*    embnew    = dwacc + 65536;                      // 65536
    unsigned* blockhist = (unsigned*)(embnew + 65536);        // 512*1024
    unsigned* blockbase = blockhist + 512 * 1024;             // 512*1024

    hipLaunchKernelGGL(k0_prep,   dim3(32),   dim3(256),  0, stream, ew, cbuf, loss_acc, dwacc);
    hipLaunchKernelGGL(k1_argmin, dim3(512),  dim3(256),  0, stream, x, ew, cbuf, out, idxbuf, blockhist);
    hipLaunchKernelGGL(k2a_scan,  dim3(256),  dim3(256),  0, stream, blockhist, blockbase, counts);
    hipLaunchKernelGGL(k2_stats,  dim3(1),    dim3(1024), 0, stream, emacs, counts, smoothed, offsets, out);
    hipLaunchKernelGGL(k3_scatter,dim3(512),  dim3(256),  0, stream, idxbuf, offsets, blockbase, toklist, clustid, out);
    hipLaunchKernelGGL(k4a_dw,    dim3(1024), dim3(256),  0, stream, x, toklist, clustid, dwacc);
    hipLaunchKernelGGL(k4b_emb,   dim3(256),  dim3(256),  0, stream, emaw, dwacc, smoothed, embnew);
    hipLaunchKernelGGL(k5_output, dim3(1024), dim3(256),  0, stream, x, embnew, idxbuf, out, loss_acc);
    hipLaunchKernelGGL(k6_loss,   dim3(1),    dim3(64),   0, stream, loss_acc, out);
}